// Round 20
// baseline (496.692 us; speedup 1.0000x reference)
//
#include <hip/hip_runtime.h>
#include <cstdint>

typedef unsigned int u32;
typedef unsigned long long u64;

#define N_BATCH 16
#define N_ROWS  25200
#define N_FEAT  85
#define N_CLS   80
#define MAX_NMS 1000
#define MAX_DET 300
#define KEY_INVALID 0xFF800000u   // key(-inf)

// ---- workspace layout (bytes) ----
#define WS_KEYS    0u                          // 16*25200*4 = 1,612,800
#define WS_CLS     1612800u                    // 16*25200*4
#define WS_SELBOX  3225600u                    // 16*1024*4*4 = 262,144
#define WS_SELOB   3487744u                    // 262,144
#define WS_SELAREA 3749888u                    // 16*1024*4 = 65,536
#define WS_SELSC   3815424u                    // 65,536
#define WS_SELCLS  3880960u                    // 65,536
#define WS_SELVAL  3946496u                    // 65,536
#define WS_GMASK   4012032u                    // 16*1000*16*8 = 2,048,000

__device__ __forceinline__ u32 score_key(float s) {
  u32 u = __float_as_uint(s);
  u32 o = (u & 0x80000000u) ? ~u : (u | 0x80000000u);
  return ~o;   // ascending key == descending score
}

__device__ __forceinline__ u64 shfl_xor_u64(u64 x, int m) {
  u32 lo = (u32)x, hi = (u32)(x >> 32);
  lo = __shfl_xor(lo, m); hi = __shfl_xor(hi, m);
  return ((u64)hi << 32) | lo;
}
__device__ __forceinline__ u64 readlane_u64(u64 x, int lane) {
  u32 lo = (u32)x, hi = (u32)(x >> 32);
  u32 rlo = (u32)__builtin_amdgcn_readlane((int)lo, lane);
  u32 rhi = (u32)__builtin_amdgcn_readlane((int)hi, lane);
  return ((u64)rhi << 32) | rlo;
}

// ---- Stage A: per-row score/class, async-pipelined LDS staging. ----
// MEASUREMENT ROUND: internal x20 repeat (pure function of pred; each rep
// re-stages and rewrites identical values; vmcnt drains to 0 at each rep's
// final iteration so the per-rep pipeline equals the validated kernel).
// Dispatch dur ~= 20*S_score -> forces k_score into rocprof top-5.
#define KS_CHUNK  32
#define KS_CBYTES (KS_CHUNK * N_FEAT * 4)     // 10880
#define KS_GRID   1792                        // 7 blocks/CU * 256 CU
#define KS_NCHUNK ((N_BATCH * N_ROWS) / KS_CHUNK)   // 12600
#define KS_REPS   20

__device__ __forceinline__ void ks_stage(const float* pred, int c, u32* lbuf,
                                         int wv, int lane) {
  const char* g = (const char*)pred + (size_t)c * KS_CBYTES;
  const int u0 = wv * 170;
  u32* l0 = lbuf + u0 * 4;
  __builtin_amdgcn_global_load_lds(
      (const __attribute__((address_space(1))) u32*)(g + (size_t)(u0 + lane) * 16),
      (__attribute__((address_space(3))) u32*)(l0), 16, 0, 0);
  __builtin_amdgcn_global_load_lds(
      (const __attribute__((address_space(1))) u32*)(g + (size_t)(u0 + 64 + lane) * 16),
      (__attribute__((address_space(3))) u32*)(l0 + 256), 16, 0, 0);
  if (lane < 42)
    __builtin_amdgcn_global_load_lds(
        (const __attribute__((address_space(1))) u32*)(g + (size_t)(u0 + 128 + lane) * 16),
        (__attribute__((address_space(3))) u32*)(l0 + 512), 16, 0, 0);
}

__global__ __launch_bounds__(256) void k_score(const float* __restrict__ pred,
                                               u32* __restrict__ keys,
                                               u32* __restrict__ clsArr) {
  __shared__ __align__(16) u32 sbuf[2][KS_CBYTES / 4];
  const int t = threadIdx.x;
  const int lane = t & 63;
  const int wv = t >> 6;
  const int row = (lane >> 3) + wv * 8;     // 0..31 within chunk
  const int sub = lane & 7;                 // class slice [10*sub, 10*sub+10)

  #pragma clang loop unroll(disable)
  for (int rep = 0; rep < KS_REPS; ++rep) {
    ks_stage(pred, blockIdx.x, sbuf[0], wv, lane);
    ks_stage(pred, blockIdx.x + KS_GRID, sbuf[1], wv, lane);

    int it = 0;
    for (int c = blockIdx.x; c < KS_NCHUNK; c += KS_GRID, ++it) {
      const bool has_next = (c + KS_GRID < KS_NCHUNK);
      if (has_next) asm volatile("s_waitcnt vmcnt(3)" ::: "memory");
      else          asm volatile("s_waitcnt vmcnt(0)" ::: "memory");
      __builtin_amdgcn_sched_barrier(0);
      __builtin_amdgcn_s_barrier();

      const u32* rp = sbuf[it & 1] + row * N_FEAT;
      float obj = __uint_as_float(rp[4]);
      float best = -__builtin_inff();
      int bi = 0;
      const u32* cp = rp + 5 + sub * 10;
      #pragma unroll
      for (int k = 0; k < 10; ++k) {
        float cc = __uint_as_float(cp[k]) * obj;         // exact reference product
        if (cc > best) { best = cc; bi = sub * 10 + k; } // strict > = first occ.
      }
      #pragma unroll
      for (int d = 1; d <= 4; d <<= 1) {
        float ob = __shfl_xor(best, d);
        int oj = __shfl_xor(bi, d);
        if (ob > best || (ob == best && oj < bi)) { best = ob; bi = oj; }
      }
      if (sub == 0) {
        bool valid = (obj > 0.3f) && (best > 0.3f);
        float s = valid ? best : -__builtin_inff();
        int gr = c * KS_CHUNK + row;
        keys[gr] = score_key(s);
        clsArr[gr] = (u32)bi;
      }
      __builtin_amdgcn_s_barrier();
      if (c + 2 * KS_GRID < KS_NCHUNK)
        ks_stage(pred, c + 2 * KS_GRID, sbuf[it & 1], wv, lane);
    }
  }
}

// ---- Stage B: per-batch exact top-1000 (desc score, asc index ties). ----
// (round-10 version, validated; frozen. Probe: S_select + G ~= 27.1 us.)
#define RPT 25   // 1024*25 = 25600 >= 25200
__global__ __launch_bounds__(1024) void k_select(const float* __restrict__ pred,
    const u32* __restrict__ keys_g, const u32* __restrict__ cls_g,
    float* __restrict__ selBox, float* __restrict__ selOb, float* __restrict__ selArea,
    float* __restrict__ selScore, float* __restrict__ selCls, u32* __restrict__ selValid) {
  extern __shared__ char smem[];
  u32* skeys = (u32*)smem;                 // [25600]  102400 B (tail uninit, masked)
  u32* hist  = (u32*)(smem + 102400);      // [256]    -> 103424
  u32* wsum  = (u32*)(smem + 103424);      // [32]     -> 103552
  u32* bc    = (u32*)(smem + 103552);      // [8]      -> 103584
  u64* items = (u64*)(smem + 103584);      // [1024]   -> 111776

  const int b = blockIdx.x;
  const int t = threadIdx.x;
  const int lane = t & 63;
  const int wv = t >> 6;

  {
    uint4* k4 = (uint4*)skeys;
    const uint4* g4 = (const uint4*)(keys_g + b * N_ROWS);
    for (int i = t; i < N_ROWS / 4; i += 1024) k4[i] = g4[i];   // coalesced
  }
  items[t] = 0xFFFFFFFF00000000ull | (u32)t;      // distinct pads, sort last
  if (t == 0) { bc[0] = 0u; bc[1] = 999u; }
  __syncthreads();

  // registers: 25 contiguous keys from LDS; pads unreachable key 0xFFFFFFFF
  u32 rk[RPT];
  const int i0 = t * RPT;
  #pragma unroll
  for (int r = 0; r < RPT; ++r) {
    u32 k = skeys[i0 + r];                 // LDS read (tail lanes read junk)
    rk[r] = (i0 + r < N_ROWS) ? k : 0xFFFFFFFFu;
  }

  // ---- radix-select T = key of rank 999 (registers -> LDS hist) ----
  for (int lev = 3; lev >= 0; --lev) {
    if (t < 256) hist[t] = 0u;
    __syncthreads();
    const u32 prefix = bc[0];
    const u32 target = bc[1];
    const int sh = lev * 8;
    if (lev == 3) {
      // wave-aggregated: few hot top-byte buckets
      #pragma unroll
      for (int r = 0; r < RPT; ++r) {
        u32 bk = rk[r] >> 24;
        u64 act = __ballot(true);
        while (act) {
          int ldr = __ffsll((unsigned long long)act) - 1;
          u32 lb = __shfl(bk, ldr);
          u64 same = __ballot(bk == lb);
          if (lane == ldr) atomicAdd(&hist[lb], (u32)__popcll(same));
          act &= ~same;
        }
      }
    } else {
      const u32 maskhi = 0xFFFFFFFFu << ((lev + 1) * 8);
      #pragma unroll
      for (int r = 0; r < RPT; ++r) {
        if ((rk[r] & maskhi) == prefix)
          atomicAdd(&hist[(rk[r] >> sh) & 255u], 1u);
      }
    }
    __syncthreads();
    if (t < 64) {                          // parallel digit scan on wave 0
      u32 c0 = hist[t*4], c1 = hist[t*4+1], c2 = hist[t*4+2], c3 = hist[t*4+3];
      u32 s4 = c0 + c1 + c2 + c3;
      u32 inc = s4;
      #pragma unroll
      for (int d = 1; d < 64; d <<= 1) { u32 o = __shfl_up(inc, d); if (lane >= d) inc += o; }
      u32 excl = inc - s4;
      u64 mb = __ballot(inc > target);
      int L = __ffsll((unsigned long long)mb) - 1;
      if (t == L) {
        u32 cum = excl; u32 d = (u32)t * 4u;
        if (cum + c0 <= target) { cum += c0; d++;
          if (cum + c1 <= target) { cum += c1; d++;
            if (cum + c2 <= target) { cum += c2; d++; } } }
        bc[0] = prefix | (d << sh);
        bc[1] = target - cum;
      }
    }
    __syncthreads();
  }
  const u32 T = bc[0];

  // ---- count from registers: contiguous ranges preserve index order ----
  u32 c0 = 0, c1 = 0;
  #pragma unroll
  for (int r = 0; r < RPT; ++r) { c0 += (rk[r] < T); c1 += (rk[r] == T); }
  u32 packed = (c0 << 16) | c1;
  u32 inc = packed;
  #pragma unroll
  for (int d = 1; d < 64; d <<= 1) { u32 o = __shfl_up(inc, d); if (lane >= d) inc += o; }
  if (lane == 63) wsum[wv] = inc;
  __syncthreads();
  if (t < 16) {
    u32 v = wsum[t]; u32 iv = v;
    #pragma unroll
    for (int d = 1; d < 16; d <<= 1) { u32 o = __shfl_up(iv, d); if (lane >= d) iv += o; }
    wsum[t] = iv - v;
    if (t == 15) bc[2] = iv;
  }
  __syncthreads();
  u32 excl = inc - packed + wsum[wv];
  u32 total0 = bc[2] >> 16;
  u32 p0 = excl >> 16;
  u32 p1 = total0 + (excl & 0xFFFFu);
  #pragma unroll
  for (int r = 0; r < RPT; ++r) {
    u32 k = rk[r];
    if (k < T)       { items[p0] = ((u64)k << 32) | (u32)(i0 + r); p0++; }
    else if (k == T) { if (p1 < (u32)MAX_NMS) items[p1] = ((u64)k << 32) | (u32)(i0 + r); p1++; }
  }
  __syncthreads();

  // ---- hybrid bitonic sort, ascending (key, idx); value in register v ----
  u64 v = items[t];
  #pragma unroll
  for (int k = 2; k <= 64; k <<= 1) {
    for (int j = k >> 1; j > 0; j >>= 1) {
      u64 p = shfl_xor_u64(v, j);
      bool keepmin = (((t & k) == 0) == ((t & j) == 0));
      v = (keepmin == (v < p)) ? v : p;
    }
  }
  for (int k = 128; k <= 1024; k <<= 1) {
    for (int j = k >> 1; j >= 64; j >>= 1) {
      items[t] = v;
      __syncthreads();
      u64 p = items[t ^ j];
      bool keepmin = (((t & k) == 0) == ((t & j) == 0));
      v = (keepmin == (v < p)) ? v : p;
      __syncthreads();
    }
    #pragma unroll
    for (int j = 32; j > 0; j >>= 1) {
      u64 p = shfl_xor_u64(v, j);
      bool keepmin = (((t & k) == 0) == ((t & j) == 0));
      v = (keepmin == (v < p)) ? v : p;
    }
  }

  // ---- gather + scatter: slot t holds rank-t item ----
  if (t < MAX_NMS) {
    u64 it = v;
    u32 key = (u32)(it >> 32);
    u32 row = (u32)(it & 0xFFFFFFFFu);
    u32 o = ~key;
    u32 sb = (o & 0x80000000u) ? (o ^ 0x80000000u) : ~o;   // invert score_key
    float score = __uint_as_float(sb);
    u32 valid = (key != KEY_INVALID) ? 1u : 0u;
    const float* p = pred + ((size_t)b * N_ROWS + row) * N_FEAT;
    float x = p[0], y = p[1], w = p[2], h = p[3];
    float x1 = x - w * 0.5f, y1 = y - h * 0.5f;
    float x2 = x + w * 0.5f, y2 = y + h * 0.5f;
    float cf = (float)cls_g[b * N_ROWS + row];
    float offv = cf * 4096.0f;
    float o0 = x1 + offv, o1 = y1 + offv, o2 = x2 + offv, o3 = y2 + offv;
    float area = (o2 - o0) * (o3 - o1);        // area from OFFSET boxes (ref)
    int idx = b * 1024 + t;
    selBox[idx * 4 + 0] = x1; selBox[idx * 4 + 1] = y1;
    selBox[idx * 4 + 2] = x2; selBox[idx * 4 + 3] = y2;
    selOb [idx * 4 + 0] = o0; selOb [idx * 4 + 1] = o1;
    selOb [idx * 4 + 2] = o2; selOb [idx * 4 + 3] = o3;
    selArea[idx] = area;
    selScore[idx] = score;
    selCls[idx] = cf;
    selValid[idx] = valid;
  }
}

// ---- Stage C: IoU>thr bitmask, UPPER TRIANGLE only (w >= i>>6). ----
// (validated rounds 7-18; frozen. Probe: S_mask + G ~= 22.1 us.)
__global__ __launch_bounds__(256) void k_mask(const float* __restrict__ selOb,
                                              const float* __restrict__ selArea,
                                              u64* __restrict__ gmask) {
  __shared__ float shob[1024 * 4];
  __shared__ float sharea[1024];
  const int chunk = blockIdx.x;
  const int b = blockIdx.y;
  const int t = threadIdx.x;
  const int lane = t & 63;
  const int wv = t >> 6;
  {
    float4* so4 = (float4*)shob;
    const float4* go4 = (const float4*)(selOb + (size_t)b * 4096);
    for (int i = t; i < 1024; i += 256) so4[i] = go4[i];
    float4* sa4 = (float4*)sharea;
    const float4* ga4 = (const float4*)(selArea + (size_t)b * 1024);
    if (t < 256) sa4[t] = ga4[t];
  }
  __syncthreads();
  const float4* job = (const float4*)shob;
  for (int k = 0; k < 8; ++k) {
    int i = chunk * 32 + wv * 8 + k;       // wave-uniform
    if (i >= MAX_NMS) break;
    float a0 = shob[i*4+0], a1 = shob[i*4+1], a2 = shob[i*4+2], a3 = shob[i*4+3];
    float aa = sharea[i];
    for (int w = (i >> 6); w < 16; ++w) {  // upper triangle only
      int j = w * 64 + lane;
      float4 bb = job[j];                  // conflict-free b128
      float aj = sharea[j];
      float lt0 = fmaxf(a0, bb.x);
      float lt1 = fmaxf(a1, bb.y);
      float rb0 = fminf(a2, bb.z);
      float rb1 = fminf(a3, bb.w);
      float ww = fmaxf(rb0 - lt0, 0.0f);
      float hh = fmaxf(rb1 - lt1, 0.0f);
      float inter = ww * hh;
      float den = aa + aj - inter + 1e-7f; // ((aa+aj)-inter)+eps, like ref
      float iou = inter / den;             // IEEE f32 div, like ref
      u64 bits = __ballot(iou > 0.45f);    // bit l <-> j = w*64+l
      if (lane == 0) gmask[((size_t)b * MAX_NMS + i) * 16 + w] = bits;
    }
  }
}

// ---- Stage D: greedy scan — scalar pick + batched apply. ----
// (round-16 version, validated; frozen.)
__global__ __launch_bounds__(256) void k_scan(const u64* __restrict__ gmask,
                                              const u32* __restrict__ selValid,
                                              const float* __restrict__ selBox,
                                              const float* __restrict__ selScore,
                                              const float* __restrict__ selCls,
                                              float* __restrict__ out) {
  extern __shared__ char smem[];
  u64* m = (u64*)smem;                       // [16000] 128000 B
  u64* aw = (u64*)(smem + 128000);           // [16]    -> 128128
  int* order = (int*)(smem + 128128);        // [300]   -> 129328
  u32* pcnt = (u32*)(smem + 129328);         // -> 129332
  const int b = blockIdx.x;
  const int t = threadIdx.x;
  const int lane = t & 63;
  const int wv = t >> 6;

  {
    const char* g = (const char*)(gmask + (size_t)b * (MAX_NMS * 16));
    for (int u = wv; u < 125; u += 4) {
      __builtin_amdgcn_global_load_lds(
          (const __attribute__((address_space(1))) u32*)(g + (size_t)u * 1024 + (size_t)lane * 16),
          (__attribute__((address_space(3))) u32*)((u32*)m + u * 256), 16, 0, 0);
    }
  }
  for (int s = t; s < 1024; s += 256) {
    u32 vv = (s < MAX_NMS) ? selValid[b * 1024 + s] : 0u;
    u64 bal = __ballot(vv != 0u);
    if ((s & 63) == 0) aw[s >> 6] = bal;
  }
  asm volatile("s_waitcnt vmcnt(0)" ::: "memory");
  __syncthreads();

  if (t < 64) {
    u64 A = (t < 16) ? aw[t] : 0ull;       // lane t<16 holds alive word t
    int cnt = 0;
    for (int w0 = 0; w0 < 16 && cnt < MAX_DET; ++w0) {
      u64 Aw = readlane_u64(A, w0);        // scalar alive word for w0
      if (Aw == 0ull) continue;
      int myrow = w0 * 64 + t;
      u64 dm = (myrow < MAX_NMS) ? m[myrow * 16 + w0] : 0ull;
      u32 dml = (u32)dm, dmh = (u32)(dm >> 32);
      u64 keepw = 0ull;
      const int cnt0 = cnt;
      while (Aw != 0ull && cnt < MAX_DET) {
        int bit = __ffsll((unsigned long long)Aw) - 1;
        keepw |= (1ull << bit);
        ++cnt;
        u64 sup = ((u64)(u32)__builtin_amdgcn_readlane((int)dmh, bit) << 32)
                |        (u32)__builtin_amdgcn_readlane((int)dml, bit);
        Aw &= ~sup;
        Aw &= ~(1ull << bit);
      }
      if ((keepw >> t) & 1ull) {
        int rank = (int)__popcll(keepw & ((1ull << t) - 1ull));
        order[cnt0 + rank] = w0 * 64 + t;
      }
      if (cnt >= MAX_DET) break;
      u64 kk = keepw;
      const u64* mr = m + (size_t)w0 * 64 * 16;
      while (kk != 0ull) {
        int b0 = __ffsll((unsigned long long)kk) - 1; kk &= kk - 1;
        int b1 = b0, b2 = b0, b3 = b0;
        if (kk) { b1 = __ffsll((unsigned long long)kk) - 1; kk &= kk - 1;
          if (kk) { b2 = __ffsll((unsigned long long)kk) - 1; kk &= kk - 1;
            if (kk) { b3 = __ffsll((unsigned long long)kk) - 1; kk &= kk - 1; } } }
        if (t < 16) {
          u64 r0 = mr[b0 * 16 + t];
          u64 r1 = mr[b1 * 16 + t];
          u64 r2 = mr[b2 * 16 + t];
          u64 r3 = mr[b3 * 16 + t];
          A &= ~(r0 | r1 | r2 | r3);
        }
      }
    }
    if (t == 0) *pcnt = (u32)cnt;
  }
  __syncthreads();
  int cnt = (int)*pcnt;
  for (int s = t; s < MAX_DET; s += 256) {
    float o0=0,o1=0,o2=0,o3=0,o4=0,o5=0;
    if (s < cnt) {
      int i = order[s];
      int idx = b * 1024 + i;
      o0 = selBox[idx*4+0]; o1 = selBox[idx*4+1];
      o2 = selBox[idx*4+2]; o3 = selBox[idx*4+3];
      o4 = selScore[idx];   o5 = selCls[idx];
    }
    float* op = out + ((size_t)b * MAX_DET + s) * 6;
    op[0]=o0; op[1]=o1; op[2]=o2; op[3]=o3; op[4]=o4; op[5]=o5;
  }
}

extern "C" void kernel_launch(void* const* d_in, const int* in_sizes, int n_in,
                              void* d_out, int out_size, void* d_ws, size_t ws_size,
                              hipStream_t stream) {
  const float* pred = (const float*)d_in[0];
  float* out = (float*)d_out;
  char* ws = (char*)d_ws;
  u32* keys     = (u32*)(ws + WS_KEYS);
  u32* cls      = (u32*)(ws + WS_CLS);
  float* selBox = (float*)(ws + WS_SELBOX);
  float* selOb  = (float*)(ws + WS_SELOB);
  float* selArea= (float*)(ws + WS_SELAREA);
  float* selScore=(float*)(ws + WS_SELSC);
  float* selCls = (float*)(ws + WS_SELCLS);
  u32* selValid = (u32*)(ws + WS_SELVAL);
  u64* gmask    = (u64*)(ws + WS_GMASK);

  k_score<<<KS_GRID, 256, 0, stream>>>(pred, keys, cls);
  k_select<<<N_BATCH, 1024, 111776, stream>>>(pred, keys, cls, selBox, selOb, selArea,
                                              selScore, selCls, selValid);
  k_mask<<<dim3(32, N_BATCH), 256, 0, stream>>>(selOb, selArea, gmask);
  k_scan<<<N_BATCH, 256, 129344, stream>>>(gmask, selValid, selBox, selScore, selCls, out);
}

// Round 21
// 97.787 us; speedup vs baseline: 5.0793x; 5.0793x over previous
//
#include <hip/hip_runtime.h>
#include <cstdint>

typedef unsigned int u32;
typedef unsigned long long u64;

#define N_BATCH 16
#define N_ROWS  25200
#define N_FEAT  85
#define N_CLS   80
#define MAX_NMS 1000
#define MAX_DET 300
#define KEY_INVALID 0xFF800000u   // key(-inf)

// ---- workspace layout (bytes) ----
#define WS_KEYS    0u                          // 16*25200*4 = 1,612,800
#define WS_CLS     1612800u                    // 16*25200*4
#define WS_SELBOX  3225600u                    // 16*1024*4*4 = 262,144
#define WS_SELOB   3487744u                    // 262,144
#define WS_SELAREA 3749888u                    // 16*1024*4 = 65,536
#define WS_SELSC   3815424u                    // 65,536
#define WS_SELCLS  3880960u                    // 65,536
#define WS_SELVAL  3946496u                    // 65,536
#define WS_GMASK   4012032u                    // 16*1000*16*8 = 2,048,000

__device__ __forceinline__ u32 score_key(float s) {
  u32 u = __float_as_uint(s);
  u32 o = (u & 0x80000000u) ? ~u : (u | 0x80000000u);
  return ~o;   // ascending key == descending score
}

__device__ __forceinline__ u64 shfl_xor_u64(u64 x, int m) {
  u32 lo = (u32)x, hi = (u32)(x >> 32);
  lo = __shfl_xor(lo, m); hi = __shfl_xor(hi, m);
  return ((u64)hi << 32) | lo;
}
__device__ __forceinline__ u64 readlane_u64(u64 x, int lane) {
  u32 lo = (u32)x, hi = (u32)(x >> 32);
  u32 rlo = (u32)__builtin_amdgcn_readlane((int)lo, lane);
  u32 rhi = (u32)__builtin_amdgcn_readlane((int)hi, lane);
  return ((u64)rhi << 32) | rlo;
}

// ---- Stage A: per-row score/class, async-pipelined LDS staging. ----
// (round-10/18 version, validated; frozen. DIRECTLY MEASURED round 20:
// S_score ~= 20.4-21.5 us at 6.4 TB/s effective = HBM/L3 BW roofline.)
#define KS_CHUNK  32
#define KS_CBYTES (KS_CHUNK * N_FEAT * 4)     // 10880
#define KS_GRID   1792                        // 7 blocks/CU * 256 CU
#define KS_NCHUNK ((N_BATCH * N_ROWS) / KS_CHUNK)   // 12600

__device__ __forceinline__ void ks_stage(const float* pred, int c, u32* lbuf,
                                         int wv, int lane) {
  const char* g = (const char*)pred + (size_t)c * KS_CBYTES;
  const int u0 = wv * 170;
  u32* l0 = lbuf + u0 * 4;
  __builtin_amdgcn_global_load_lds(
      (const __attribute__((address_space(1))) u32*)(g + (size_t)(u0 + lane) * 16),
      (__attribute__((address_space(3))) u32*)(l0), 16, 0, 0);
  __builtin_amdgcn_global_load_lds(
      (const __attribute__((address_space(1))) u32*)(g + (size_t)(u0 + 64 + lane) * 16),
      (__attribute__((address_space(3))) u32*)(l0 + 256), 16, 0, 0);
  if (lane < 42)
    __builtin_amdgcn_global_load_lds(
        (const __attribute__((address_space(1))) u32*)(g + (size_t)(u0 + 128 + lane) * 16),
        (__attribute__((address_space(3))) u32*)(l0 + 512), 16, 0, 0);
}

__global__ __launch_bounds__(256) void k_score(const float* __restrict__ pred,
                                               u32* __restrict__ keys,
                                               u32* __restrict__ clsArr) {
  __shared__ __align__(16) u32 sbuf[2][KS_CBYTES / 4];
  const int t = threadIdx.x;
  const int lane = t & 63;
  const int wv = t >> 6;
  const int row = (lane >> 3) + wv * 8;     // 0..31 within chunk
  const int sub = lane & 7;                 // class slice [10*sub, 10*sub+10)

  ks_stage(pred, blockIdx.x, sbuf[0], wv, lane);
  ks_stage(pred, blockIdx.x + KS_GRID, sbuf[1], wv, lane);

  int it = 0;
  for (int c = blockIdx.x; c < KS_NCHUNK; c += KS_GRID, ++it) {
    const bool has_next = (c + KS_GRID < KS_NCHUNK);
    if (has_next) asm volatile("s_waitcnt vmcnt(3)" ::: "memory");
    else          asm volatile("s_waitcnt vmcnt(0)" ::: "memory");
    __builtin_amdgcn_sched_barrier(0);
    __builtin_amdgcn_s_barrier();

    const u32* rp = sbuf[it & 1] + row * N_FEAT;
    float obj = __uint_as_float(rp[4]);
    float best = -__builtin_inff();
    int bi = 0;
    const u32* cp = rp + 5 + sub * 10;
    #pragma unroll
    for (int k = 0; k < 10; ++k) {
      float cc = __uint_as_float(cp[k]) * obj;         // exact reference product
      if (cc > best) { best = cc; bi = sub * 10 + k; } // strict > = first occ.
    }
    #pragma unroll
    for (int d = 1; d <= 4; d <<= 1) {
      float ob = __shfl_xor(best, d);
      int oj = __shfl_xor(bi, d);
      if (ob > best || (ob == best && oj < bi)) { best = ob; bi = oj; }
    }
    if (sub == 0) {
      bool valid = (obj > 0.3f) && (best > 0.3f);
      float s = valid ? best : -__builtin_inff();
      int gr = c * KS_CHUNK + row;
      keys[gr] = score_key(s);
      clsArr[gr] = (u32)bi;
    }
    __builtin_amdgcn_s_barrier();
    if (c + 2 * KS_GRID < KS_NCHUNK)
      ks_stage(pred, c + 2 * KS_GRID, sbuf[it & 1], wv, lane);
  }
}

// ---- Stage B: per-batch exact top-1000 (desc score, asc index ties). ----
// (round-10 version, validated; frozen. S_select ~= 24.9 us.)
#define RPT 25   // 1024*25 = 25600 >= 25200
__global__ __launch_bounds__(1024) void k_select(const float* __restrict__ pred,
    const u32* __restrict__ keys_g, const u32* __restrict__ cls_g,
    float* __restrict__ selBox, float* __restrict__ selOb, float* __restrict__ selArea,
    float* __restrict__ selScore, float* __restrict__ selCls, u32* __restrict__ selValid) {
  extern __shared__ char smem[];
  u32* skeys = (u32*)smem;                 // [25600]  102400 B (tail uninit, masked)
  u32* hist  = (u32*)(smem + 102400);      // [256]    -> 103424
  u32* wsum  = (u32*)(smem + 103424);      // [32]     -> 103552
  u32* bc    = (u32*)(smem + 103552);      // [8]      -> 103584
  u64* items = (u64*)(smem + 103584);      // [1024]   -> 111776

  const int b = blockIdx.x;
  const int t = threadIdx.x;
  const int lane = t & 63;
  const int wv = t >> 6;

  {
    uint4* k4 = (uint4*)skeys;
    const uint4* g4 = (const uint4*)(keys_g + b * N_ROWS);
    for (int i = t; i < N_ROWS / 4; i += 1024) k4[i] = g4[i];   // coalesced
  }
  items[t] = 0xFFFFFFFF00000000ull | (u32)t;      // distinct pads, sort last
  if (t == 0) { bc[0] = 0u; bc[1] = 999u; }
  __syncthreads();

  // registers: 25 contiguous keys from LDS; pads unreachable key 0xFFFFFFFF
  u32 rk[RPT];
  const int i0 = t * RPT;
  #pragma unroll
  for (int r = 0; r < RPT; ++r) {
    u32 k = skeys[i0 + r];                 // LDS read (tail lanes read junk)
    rk[r] = (i0 + r < N_ROWS) ? k : 0xFFFFFFFFu;
  }

  // ---- radix-select T = key of rank 999 (registers -> LDS hist) ----
  for (int lev = 3; lev >= 0; --lev) {
    if (t < 256) hist[t] = 0u;
    __syncthreads();
    const u32 prefix = bc[0];
    const u32 target = bc[1];
    const int sh = lev * 8;
    if (lev == 3) {
      // wave-aggregated: few hot top-byte buckets
      #pragma unroll
      for (int r = 0; r < RPT; ++r) {
        u32 bk = rk[r] >> 24;
        u64 act = __ballot(true);
        while (act) {
          int ldr = __ffsll((unsigned long long)act) - 1;
          u32 lb = __shfl(bk, ldr);
          u64 same = __ballot(bk == lb);
          if (lane == ldr) atomicAdd(&hist[lb], (u32)__popcll(same));
          act &= ~same;
        }
      }
    } else {
      const u32 maskhi = 0xFFFFFFFFu << ((lev + 1) * 8);
      #pragma unroll
      for (int r = 0; r < RPT; ++r) {
        if ((rk[r] & maskhi) == prefix)
          atomicAdd(&hist[(rk[r] >> sh) & 255u], 1u);
      }
    }
    __syncthreads();
    if (t < 64) {                          // parallel digit scan on wave 0
      u32 c0 = hist[t*4], c1 = hist[t*4+1], c2 = hist[t*4+2], c3 = hist[t*4+3];
      u32 s4 = c0 + c1 + c2 + c3;
      u32 inc = s4;
      #pragma unroll
      for (int d = 1; d < 64; d <<= 1) { u32 o = __shfl_up(inc, d); if (lane >= d) inc += o; }
      u32 excl = inc - s4;
      u64 mb = __ballot(inc > target);
      int L = __ffsll((unsigned long long)mb) - 1;
      if (t == L) {
        u32 cum = excl; u32 d = (u32)t * 4u;
        if (cum + c0 <= target) { cum += c0; d++;
          if (cum + c1 <= target) { cum += c1; d++;
            if (cum + c2 <= target) { cum += c2; d++; } } }
        bc[0] = prefix | (d << sh);
        bc[1] = target - cum;
      }
    }
    __syncthreads();
  }
  const u32 T = bc[0];

  // ---- count from registers: contiguous ranges preserve index order ----
  u32 c0 = 0, c1 = 0;
  #pragma unroll
  for (int r = 0; r < RPT; ++r) { c0 += (rk[r] < T); c1 += (rk[r] == T); }
  u32 packed = (c0 << 16) | c1;
  u32 inc = packed;
  #pragma unroll
  for (int d = 1; d < 64; d <<= 1) { u32 o = __shfl_up(inc, d); if (lane >= d) inc += o; }
  if (lane == 63) wsum[wv] = inc;
  __syncthreads();
  if (t < 16) {
    u32 v = wsum[t]; u32 iv = v;
    #pragma unroll
    for (int d = 1; d < 16; d <<= 1) { u32 o = __shfl_up(iv, d); if (lane >= d) iv += o; }
    wsum[t] = iv - v;
    if (t == 15) bc[2] = iv;
  }
  __syncthreads();
  u32 excl = inc - packed + wsum[wv];
  u32 total0 = bc[2] >> 16;
  u32 p0 = excl >> 16;
  u32 p1 = total0 + (excl & 0xFFFFu);
  #pragma unroll
  for (int r = 0; r < RPT; ++r) {
    u32 k = rk[r];
    if (k < T)       { items[p0] = ((u64)k << 32) | (u32)(i0 + r); p0++; }
    else if (k == T) { if (p1 < (u32)MAX_NMS) items[p1] = ((u64)k << 32) | (u32)(i0 + r); p1++; }
  }
  __syncthreads();

  // ---- hybrid bitonic sort, ascending (key, idx); value in register v ----
  u64 v = items[t];
  #pragma unroll
  for (int k = 2; k <= 64; k <<= 1) {
    for (int j = k >> 1; j > 0; j >>= 1) {
      u64 p = shfl_xor_u64(v, j);
      bool keepmin = (((t & k) == 0) == ((t & j) == 0));
      v = (keepmin == (v < p)) ? v : p;
    }
  }
  for (int k = 128; k <= 1024; k <<= 1) {
    for (int j = k >> 1; j >= 64; j >>= 1) {
      items[t] = v;
      __syncthreads();
      u64 p = items[t ^ j];
      bool keepmin = (((t & k) == 0) == ((t & j) == 0));
      v = (keepmin == (v < p)) ? v : p;
      __syncthreads();
    }
    #pragma unroll
    for (int j = 32; j > 0; j >>= 1) {
      u64 p = shfl_xor_u64(v, j);
      bool keepmin = (((t & k) == 0) == ((t & j) == 0));
      v = (keepmin == (v < p)) ? v : p;
    }
  }

  // ---- gather + scatter: slot t holds rank-t item ----
  if (t < MAX_NMS) {
    u64 it = v;
    u32 key = (u32)(it >> 32);
    u32 row = (u32)(it & 0xFFFFFFFFu);
    u32 o = ~key;
    u32 sb = (o & 0x80000000u) ? (o ^ 0x80000000u) : ~o;   // invert score_key
    float score = __uint_as_float(sb);
    u32 valid = (key != KEY_INVALID) ? 1u : 0u;
    const float* p = pred + ((size_t)b * N_ROWS + row) * N_FEAT;
    float x = p[0], y = p[1], w = p[2], h = p[3];
    float x1 = x - w * 0.5f, y1 = y - h * 0.5f;
    float x2 = x + w * 0.5f, y2 = y + h * 0.5f;
    float cf = (float)cls_g[b * N_ROWS + row];
    float offv = cf * 4096.0f;
    float o0 = x1 + offv, o1 = y1 + offv, o2 = x2 + offv, o3 = y2 + offv;
    float area = (o2 - o0) * (o3 - o1);        // area from OFFSET boxes (ref)
    int idx = b * 1024 + t;
    selBox[idx * 4 + 0] = x1; selBox[idx * 4 + 1] = y1;
    selBox[idx * 4 + 2] = x2; selBox[idx * 4 + 3] = y2;
    selOb [idx * 4 + 0] = o0; selOb [idx * 4 + 1] = o1;
    selOb [idx * 4 + 2] = o2; selOb [idx * 4 + 3] = o3;
    selArea[idx] = area;
    selScore[idx] = score;
    selCls[idx] = cf;
    selValid[idx] = valid;
  }
}

// ---- Stage C: IoU>thr bitmask, upper triangle, BALANCED + SoA. ----
// Changes vs validated round-18 (math bit-identical, writes identical set):
// 1. Row striping: wave g (of 256/batch, grid (64,16) x 4 waves) handles
//    rows i = g, g+256, g+512, g+768 -> ~37 word-iters/wave balanced
//    (was: contiguous rows -> worst block 128 iters/wave = wall time).
// 2. SoA box staging (shx1/shy1/shx2/shy2/sharea): inner read lane-stride
//    4B -> conflict-free (was float4 lane-stride 16B -> 8-way bank
//    conflict, 2.94x per m136). Same values, same expression order.
__global__ __launch_bounds__(256) void k_mask(const float* __restrict__ selOb,
                                              const float* __restrict__ selArea,
                                              u64* __restrict__ gmask) {
  __shared__ float shx1[1024], shy1[1024], shx2[1024], shy2[1024];
  __shared__ float sharea[1024];
  const int b = blockIdx.y;
  const int t = threadIdx.x;
  const int lane = t & 63;
  const int wv = t >> 6;
  for (int i = t; i < 1024; i += 256) {
    float4 v = ((const float4*)(selOb + (size_t)b * 4096))[i];  // coalesced
    shx1[i] = v.x; shy1[i] = v.y; shx2[i] = v.z; shy2[i] = v.w;
    sharea[i] = selArea[b * 1024 + i];
  }
  __syncthreads();
  const int gw = blockIdx.x * 4 + wv;      // 0..255 within batch
  for (int i = gw; i < MAX_NMS; i += 256) {  // striped rows, wave-uniform
    float a0 = shx1[i], a1 = shy1[i], a2 = shx2[i], a3 = shy2[i];  // broadcast
    float aa = sharea[i];
    for (int w = (i >> 6); w < 16; ++w) {  // upper triangle only
      int j = w * 64 + lane;
      float lt0 = fmaxf(a0, shx1[j]);      // conflict-free lane-stride reads
      float lt1 = fmaxf(a1, shy1[j]);
      float rb0 = fminf(a2, shx2[j]);
      float rb1 = fminf(a3, shy2[j]);
      float ww = fmaxf(rb0 - lt0, 0.0f);
      float hh = fmaxf(rb1 - lt1, 0.0f);
      float inter = ww * hh;
      float den = aa + sharea[j] - inter + 1e-7f; // ((aa+aj)-inter)+eps, like ref
      float iou = inter / den;             // IEEE f32 div, like ref
      u64 bits = __ballot(iou > 0.45f);    // bit l <-> j = w*64+l
      if (lane == 0) gmask[((size_t)b * MAX_NMS + i) * 16 + w] = bits;
    }
  }
}

// ---- Stage D: greedy scan — scalar pick + batched apply. ----
// (round-16 version, validated; frozen. S_scan ~= 22 us.)
__global__ __launch_bounds__(256) void k_scan(const u64* __restrict__ gmask,
                                              const u32* __restrict__ selValid,
                                              const float* __restrict__ selBox,
                                              const float* __restrict__ selScore,
                                              const float* __restrict__ selCls,
                                              float* __restrict__ out) {
  extern __shared__ char smem[];
  u64* m = (u64*)smem;                       // [16000] 128000 B
  u64* aw = (u64*)(smem + 128000);           // [16]    -> 128128
  int* order = (int*)(smem + 128128);        // [300]   -> 129328
  u32* pcnt = (u32*)(smem + 129328);         // -> 129332
  const int b = blockIdx.x;
  const int t = threadIdx.x;
  const int lane = t & 63;
  const int wv = t >> 6;

  {
    const char* g = (const char*)(gmask + (size_t)b * (MAX_NMS * 16));
    for (int u = wv; u < 125; u += 4) {
      __builtin_amdgcn_global_load_lds(
          (const __attribute__((address_space(1))) u32*)(g + (size_t)u * 1024 + (size_t)lane * 16),
          (__attribute__((address_space(3))) u32*)((u32*)m + u * 256), 16, 0, 0);
    }
  }
  for (int s = t; s < 1024; s += 256) {
    u32 vv = (s < MAX_NMS) ? selValid[b * 1024 + s] : 0u;
    u64 bal = __ballot(vv != 0u);
    if ((s & 63) == 0) aw[s >> 6] = bal;
  }
  asm volatile("s_waitcnt vmcnt(0)" ::: "memory");
  __syncthreads();

  if (t < 64) {
    u64 A = (t < 16) ? aw[t] : 0ull;       // lane t<16 holds alive word t
    int cnt = 0;
    for (int w0 = 0; w0 < 16 && cnt < MAX_DET; ++w0) {
      u64 Aw = readlane_u64(A, w0);        // scalar alive word for w0
      if (Aw == 0ull) continue;
      int myrow = w0 * 64 + t;
      u64 dm = (myrow < MAX_NMS) ? m[myrow * 16 + w0] : 0ull;
      u32 dml = (u32)dm, dmh = (u32)(dm >> 32);
      u64 keepw = 0ull;
      const int cnt0 = cnt;
      while (Aw != 0ull && cnt < MAX_DET) {
        int bit = __ffsll((unsigned long long)Aw) - 1;
        keepw |= (1ull << bit);
        ++cnt;
        u64 sup = ((u64)(u32)__builtin_amdgcn_readlane((int)dmh, bit) << 32)
                |        (u32)__builtin_amdgcn_readlane((int)dml, bit);
        Aw &= ~sup;
        Aw &= ~(1ull << bit);
      }
      if ((keepw >> t) & 1ull) {
        int rank = (int)__popcll(keepw & ((1ull << t) - 1ull));
        order[cnt0 + rank] = w0 * 64 + t;
      }
      if (cnt >= MAX_DET) break;
      u64 kk = keepw;
      const u64* mr = m + (size_t)w0 * 64 * 16;
      while (kk != 0ull) {
        int b0 = __ffsll((unsigned long long)kk) - 1; kk &= kk - 1;
        int b1 = b0, b2 = b0, b3 = b0;
        if (kk) { b1 = __ffsll((unsigned long long)kk) - 1; kk &= kk - 1;
          if (kk) { b2 = __ffsll((unsigned long long)kk) - 1; kk &= kk - 1;
            if (kk) { b3 = __ffsll((unsigned long long)kk) - 1; kk &= kk - 1; } } }
        if (t < 16) {
          u64 r0 = mr[b0 * 16 + t];
          u64 r1 = mr[b1 * 16 + t];
          u64 r2 = mr[b2 * 16 + t];
          u64 r3 = mr[b3 * 16 + t];
          A &= ~(r0 | r1 | r2 | r3);
        }
      }
    }
    if (t == 0) *pcnt = (u32)cnt;
  }
  __syncthreads();
  int cnt = (int)*pcnt;
  for (int s = t; s < MAX_DET; s += 256) {
    float o0=0,o1=0,o2=0,o3=0,o4=0,o5=0;
    if (s < cnt) {
      int i = order[s];
      int idx = b * 1024 + i;
      o0 = selBox[idx*4+0]; o1 = selBox[idx*4+1];
      o2 = selBox[idx*4+2]; o3 = selBox[idx*4+3];
      o4 = selScore[idx];   o5 = selCls[idx];
    }
    float* op = out + ((size_t)b * MAX_DET + s) * 6;
    op[0]=o0; op[1]=o1; op[2]=o2; op[3]=o3; op[4]=o4; op[5]=o5;
  }
}

extern "C" void kernel_launch(void* const* d_in, const int* in_sizes, int n_in,
                              void* d_out, int out_size, void* d_ws, size_t ws_size,
                              hipStream_t stream) {
  const float* pred = (const float*)d_in[0];
  float* out = (float*)d_out;
  char* ws = (char*)d_ws;
  u32* keys     = (u32*)(ws + WS_KEYS);
  u32* cls      = (u32*)(ws + WS_CLS);
  float* selBox = (float*)(ws + WS_SELBOX);
  float* selOb  = (float*)(ws + WS_SELOB);
  float* selArea= (float*)(ws + WS_SELAREA);
  float* selScore=(float*)(ws + WS_SELSC);
  float* selCls = (float*)(ws + WS_SELCLS);
  u32* selValid = (u32*)(ws + WS_SELVAL);
  u64* gmask    = (u64*)(ws + WS_GMASK);

  k_score<<<KS_GRID, 256, 0, stream>>>(pred, keys, cls);
  k_select<<<N_BATCH, 1024, 111776, stream>>>(pred, keys, cls, selBox, selOb, selArea,
                                              selScore, selCls, selValid);
  k_mask<<<dim3(64, N_BATCH), 256, 0, stream>>>(selOb, selArea, gmask);
  k_scan<<<N_BATCH, 256, 129344, stream>>>(gmask, selValid, selBox, selScore, selCls, out);
}